// Round 18
// baseline (141.836 us; speedup 1.0000x reference)
//
#include <hip/hip_runtime.h>
#include <stdint.h>

typedef __attribute__((ext_vector_type(4))) float f32x4;
typedef __attribute__((ext_vector_type(16))) float f32x16;
typedef __attribute__((ext_vector_type(8))) __bf16 bf16x8;
typedef __attribute__((ext_vector_type(2))) unsigned int u32v2;

#define GLDS(g, s) __builtin_amdgcn_global_load_lds( \
    (const __attribute__((address_space(1))) void*)(g), \
    (__attribute__((address_space(3))) void*)(s), 16, 0, 0)

// row-aware LDS chunk swizzle: distinct for rows 8 apart
#define SWZ8(r) ((((r) ^ ((r) >> 3))) & 7)

__device__ inline float fast_exp2(float x){
#if __has_builtin(__builtin_amdgcn_exp2f)
  return __builtin_amdgcn_exp2f(x);
#else
  float r; asm("v_exp_f32 %0, %1" : "=v"(r) : "v"(x)); return r;
#endif
}

__device__ inline unsigned short f2bf(float f){
  union { float f; unsigned int u; } v; v.f = f;
  unsigned int u = v.u;
  unsigned int r = (u + 0x7fffu + ((u >> 16) & 1u)) >> 16;
  return (unsigned short)r;
}

// ---------------- prep: fp32->bf16 cvt (blocks 0..2047) + both W transposes (2048..3071) ----------------
__global__ __launch_bounds__(256) void prep(const float* __restrict__ x,
                                            const float* __restrict__ Wqkv,
                                            const float* __restrict__ Wout,
                                            unsigned short* __restrict__ y,
                                            unsigned short* __restrict__ wqkvT,
                                            unsigned short* __restrict__ woutT){
  __shared__ float tile[64][65];
  const int bx = blockIdx.x;
  const int t = threadIdx.x;
  if (bx < 2048){
    const size_t i = ((size_t)bx * 256 + t) * 8;
    float4 a = *reinterpret_cast<const float4*>(x + i);
    float4 b = *reinterpret_cast<const float4*>(x + i + 4);
    uint4 o;
    o.x = (unsigned)f2bf(a.x) | ((unsigned)f2bf(a.y) << 16);
    o.y = (unsigned)f2bf(a.z) | ((unsigned)f2bf(a.w) << 16);
    o.z = (unsigned)f2bf(b.x) | ((unsigned)f2bf(b.y) << 16);
    o.w = (unsigned)f2bf(b.z) | ((unsigned)f2bf(b.w) << 16);
    *reinterpret_cast<uint4*>(y + i) = o;
    return;
  }
  const int tb = bx - 2048;           // [0,1024): 64 n-blocks x 16 k-blocks
  const int nb = tb & 63;
  const int k0 = (tb >> 6) * 64;
  const float* W; unsigned short* WT; int N, n0;
  if (nb < 48){ W = Wqkv; WT = wqkvT; N = 3072; n0 = nb * 64; }
  else        { W = Wout; WT = woutT; N = 1024; n0 = (nb - 48) * 64; }
  #pragma unroll
  for (int p = 0; p < 16; p++){
    int idx = p * 256 + t; int r = idx >> 6, c = idx & 63;
    tile[r][c] = W[(size_t)(k0 + r) * N + n0 + c];
  }
  __syncthreads();
  #pragma unroll
  for (int p = 0; p < 16; p++){
    int idx = p * 256 + t; int r = idx >> 6, c = idx & 63;
    WT[(size_t)(n0 + r) * 1024 + k0 + c] = f2bf(tile[c][r]);
  }
}

// ---------------- GEMM ----------------
// MODE 0: 128x128 tile, BK=64 (16 K-iters, half the barrier drains); staging =
//         8 GLDS/wave (8 rows x 64 elems each, wave-linear dest). Epilogue
//         re-tile buffer OVERLAYS the K-loop staging LDS (36 KB total).
// MODE 1: 128x64 tile, BK=32 (round-14-verified loop) + same overlay.
template<int MODE>
__global__ __launch_bounds__(256) void gemm_bt(
    const unsigned short* __restrict__ X,
    const unsigned short* __restrict__ WT,
    const float* __restrict__ bias,
    unsigned short* __restrict__ oq,
    unsigned short* __restrict__ ok,
    unsigned short* __restrict__ ovt,   // [BH][64][S] (V transposed), MODE 0 only
    float* __restrict__ ofp)
{
  constexpr int Kdim = 1024;
  constexpr int BN = (MODE == 0) ? 128 : 64;
  constexpr int JN = (MODE == 0) ? 4 : 2;     // n-frags per wave
  __shared__ __align__(16) unsigned short SMEM[18432];   // K-loop staging / epilogue re-tile
  const int t  = threadIdx.x;
  const int l  = t & 63;
  const int w  = t >> 6;
  const int lr = l & 15, lg = l >> 4;
  const int wr = w >> 1, wc = w & 1;

  // XCD-chunked bijective swizzle (nwg = 768 / 512, both % 8 == 0)
  const unsigned nx = gridDim.x;
  const unsigned nwg = nx * gridDim.y;
  const unsigned f0 = blockIdx.y * nx + blockIdx.x;
  const unsigned f  = (f0 & 7) * (nwg >> 3) + (f0 >> 3);
  const int m0 = (int)(f / nx) * 128;
  const int n0 = (int)(f % nx) * BN;

  f32x4 zero4 = {0.f, 0.f, 0.f, 0.f};
  f32x4 acc[4][JN];
  #pragma unroll
  for (int i = 0; i < 4; i++)
    #pragma unroll
    for (int j = 0; j < JN; j++) acc[i][j] = zero4;

  if constexpr (MODE == 0){
    unsigned short* As = SMEM;            // [128][64]
    unsigned short* Bs = SMEM + 8192;     // [128][64]
    // staging: each GLDS = 64 lanes x 16B = 8 rows of 64 elems; lane -> (row l>>3, chunk l&7)
    const int srow = l >> 3;
    const int sch  = (l & 7) * 8;
    const unsigned short* gA[4];
    const unsigned short* gB[4];
    unsigned short* lA[4];
    unsigned short* lB[4];
    #pragma unroll
    for (int i = 0; i < 4; i++){
      gA[i] = X  + (size_t)(m0 + w * 32 + i * 8 + srow) * Kdim + sch;
      lA[i] = &As[(w * 32 + i * 8) * 64];
      gB[i] = WT + (size_t)(n0 + w * 32 + i * 8 + srow) * Kdim + sch;
      lB[i] = &Bs[(w * 32 + i * 8) * 64];
    }
    for (int kt = 0; kt < 16; ++kt){
      const int kb = kt * 64;
      __syncthreads();
      #pragma unroll
      for (int i = 0; i < 4; i++) GLDS(gA[i] + kb, lA[i]);
      #pragma unroll
      for (int i = 0; i < 4; i++) GLDS(gB[i] + kb, lB[i]);
      __syncthreads();
      bf16x8 af[4][2], bfr[4][2];
      #pragma unroll
      for (int i = 0; i < 4; i++){
        const int ro = (wr * 64 + i * 16 + lr) * 64 + lg * 8;
        af[i][0] = *reinterpret_cast<const bf16x8*>(&As[ro]);
        af[i][1] = *reinterpret_cast<const bf16x8*>(&As[ro + 32]);
      }
      #pragma unroll
      for (int j = 0; j < 4; j++){
        const int ro = (wc * 64 + j * 16 + lr) * 64 + lg * 8;
        bfr[j][0] = *reinterpret_cast<const bf16x8*>(&Bs[ro]);
        bfr[j][1] = *reinterpret_cast<const bf16x8*>(&Bs[ro + 32]);
      }
      __builtin_amdgcn_s_setprio(1);
      #pragma unroll
      for (int i = 0; i < 4; i++)
        #pragma unroll
        for (int j = 0; j < 4; j++){
          acc[i][j] = __builtin_amdgcn_mfma_f32_16x16x32_bf16(af[i][0], bfr[j][0], acc[i][j], 0, 0, 0);
          acc[i][j] = __builtin_amdgcn_mfma_f32_16x16x32_bf16(af[i][1], bfr[j][1], acc[i][j], 0, 0, 0);
        }
      __builtin_amdgcn_s_setprio(0);
    }
  } else {
    unsigned short* As = SMEM;            // [128][32]
    unsigned short* Bs = SMEM + 4096;     // [64][32]
    const int lrow = l >> 2;
    const int lch  = (l & 3) * 8;
    const unsigned short* gA0 = X  + (size_t)(m0 + w * 16 + lrow) * Kdim + lch;
    const unsigned short* gA1 = gA0 + (size_t)64 * Kdim;
    const unsigned short* gB0 = WT + (size_t)(n0 + w * 16 + lrow) * Kdim + lch;
    unsigned short* lA0 = &As[(w * 16) * 32];
    unsigned short* lA1 = &As[(64 + w * 16) * 32];
    unsigned short* lB0 = &Bs[(w * 16) * 32];
    const int aoff = (wr * 64 + lr) * 32 + lg * 8;
    const int boff = (wc * 32 + lr) * 32 + lg * 8;
    for (int kt = 0; kt < 32; ++kt){
      const int kb = kt * 32;
      __syncthreads();
      GLDS(gA0 + kb, lA0);
      GLDS(gA1 + kb, lA1);
      GLDS(gB0 + kb, lB0);
      __syncthreads();
      bf16x8 af[4], bfr[2];
      #pragma unroll
      for (int i = 0; i < 4; i++)  af[i]  = *reinterpret_cast<const bf16x8*>(&As[aoff + i * 16 * 32]);
      #pragma unroll
      for (int j = 0; j < 2; j++) bfr[j] = *reinterpret_cast<const bf16x8*>(&Bs[boff + j * 16 * 32]);
      __builtin_amdgcn_s_setprio(1);
      #pragma unroll
      for (int i = 0; i < 4; i++)
        #pragma unroll
        for (int j = 0; j < 2; j++)
          acc[i][j] = __builtin_amdgcn_mfma_f32_16x16x32_bf16(af[i], bfr[j], acc[i][j], 0, 0, 0);
      __builtin_amdgcn_s_setprio(0);
    }
  }

  const int mbg = m0 + wr * 64;               // wave's global m-base (64-aligned)
  const int nb  = n0 + wc * (BN / 2);         // wave's global n-base
  __syncthreads();                            // all waves done with staging LDS -> overlay
  if constexpr (MODE == 0){
    unsigned short* E = SMEM + w * 4608;      // per-wave [64][72] bf16 re-tile
    const int which = n0 >> 10;               // 0=Q,1=K,2=V (128-tile wholly inside one)
    const int h = (nb >> 6) & 15;             // wave-uniform head
    const float qs = (which == 0) ? 0.18033688011f : 1.0f;   // 0.125*log2(e)
    #pragma unroll
    for (int j = 0; j < 4; j++){
      const float bs = bias[nb + j * 16 + lr];
      const int nloc = j * 16 + lr;
      #pragma unroll
      for (int i = 0; i < 4; i++){
        #pragma unroll
        for (int r = 0; r < 4; r++){
          const int mloc = i * 16 + 4 * lg + r;
          const unsigned short vv = f2bf((acc[i][j][r] + bs) * qs);
          if (which == 2) E[nloc * 72 + mloc] = vv;   // [d][s] -> V pre-transposed
          else            E[mloc * 72 + nloc] = vv;   // [s][d]
        }
      }
    }
    asm volatile("s_waitcnt lgkmcnt(0)" ::: "memory");
    __builtin_amdgcn_sched_barrier(0);
    const int b = mbg >> 11, sib = mbg & 2047;
    const size_t bh = (size_t)(b * 16 + h);
    if (which == 2){
      unsigned short* dst = ovt + bh * 64 * 2048 + sib;
      #pragma unroll
      for (int it = 0; it < 8; ++it){
        const int d = it * 8 + (l >> 3);
        const int sc8 = (l & 7) * 8;
        uint4 xv = *reinterpret_cast<const uint4*>(&E[d * 72 + sc8]);
        *reinterpret_cast<uint4*>(dst + (size_t)d * 2048 + sc8) = xv;
      }
    } else {
      unsigned short* dst = (which == 0 ? oq : ok) + (bh * 2048 + sib) * 64;
      #pragma unroll
      for (int it = 0; it < 8; ++it){
        const int sl = it * 8 + (l >> 3);
        const int dc8 = (l & 7) * 8;
        uint4 xv = *reinterpret_cast<const uint4*>(&E[sl * 72 + dc8]);
        *reinterpret_cast<uint4*>(dst + (size_t)sl * 64 + dc8) = xv;
      }
    }
  } else {
    float* E = reinterpret_cast<float*>(SMEM) + w * 2304;   // per-wave [64][36] fp32
    #pragma unroll
    for (int j = 0; j < JN; j++){
      const float bs = bias[nb + j * 16 + lr];
      const int nloc = j * 16 + lr;
      #pragma unroll
      for (int i = 0; i < 4; i++){
        #pragma unroll
        for (int r = 0; r < 4; r++){
          const int mloc = i * 16 + 4 * lg + r;
          E[mloc * 36 + nloc] = acc[i][j][r] + bs;
        }
      }
    }
    asm volatile("s_waitcnt lgkmcnt(0)" ::: "memory");
    __builtin_amdgcn_sched_barrier(0);
    #pragma unroll
    for (int it = 0; it < 8; ++it){
      const int ml = it * 8 + (l >> 3);
      const int nc = (l & 7) * 4;
      uint4 xv = *reinterpret_cast<const uint4*>(&E[ml * 36 + nc]);
      *reinterpret_cast<uint4*>(ofp + (size_t)(mbg + ml) * 1024 + nb + nc) = xv;
    }
  }
}

// ---------------- Flash attention fwd (round-16-verified, verbatim) ----------------
// 32x32x16, 32 q/wave, in-register P via cvt_pk + permlane32_swap; reg-staged
// K/V prefetch (T14: loads stay in flight across the barrier -- GLDS variant
// regressed in round 17 because __syncthreads must drain vmcnt for LDS-writing
// loads).
__global__ __launch_bounds__(256) void attn_fwd(
    const unsigned short* __restrict__ Q,   // [BH][S][64]
    const unsigned short* __restrict__ Kt,  // [BH][S][64]
    const unsigned short* __restrict__ VT,  // [BH][64][S]
    unsigned short* __restrict__ O)         // [B][S][1024]
{
  __shared__ __align__(16) unsigned short Ks[2][4096];
  __shared__ __align__(16) unsigned short Vs[2][4096];
  const int t = threadIdx.x;
  const int l = t & 63, w = t >> 6;
  const int q5 = l & 31;          // lane's q (B/D col) -- also key/d row for A-frags
  const int hi = l >> 5;          // k-group selector

  const unsigned flat = blockIdx.y * gridDim.x + blockIdx.x;   // 512 wgs
  const unsigned fl = (flat & 7) * 64 + (flat >> 3);           // XCD-chunked (bijective)
  const int bh = fl >> 4;
  const int q0 = (fl & 15) * 128 + w * 32;

  const unsigned short* Qb = Q + ((size_t)bh * 2048 + q0) * 64;
  bf16x8 qf0 = *reinterpret_cast<const bf16x8*>(Qb + (size_t)q5 * 64 +  0 + hi * 8);
  bf16x8 qf1 = *reinterpret_cast<const bf16x8*>(Qb + (size_t)q5 * 64 + 16 + hi * 8);
  bf16x8 qf2 = *reinterpret_cast<const bf16x8*>(Qb + (size_t)q5 * 64 + 32 + hi * 8);
  bf16x8 qf3 = *reinterpret_cast<const bf16x8*>(Qb + (size_t)q5 * 64 + 48 + hi * 8);
  const unsigned short* Kb = Kt + (size_t)bh * 2048 * 64;
  const unsigned short* Vb = VT + (size_t)bh * 64 * 2048;

  union U8 { unsigned u[4]; uint4 u4; bf16x8 b; };

  // staging map: thread t -> (row r, 16B chunk c); SWZ'd LDS dest
  const int r0 = t >> 3,        c0 = t & 7;
  const int r1 = 32 + (t >> 3), c1 = t & 7;
  const int kof0 = r0 * 64 + ((c0 ^ SWZ8(r0)) * 8);
  const int kof1 = r1 * 64 + ((c1 ^ SWZ8(r1)) * 8);
  const unsigned short* gK0 = Kb + r0 * 64 + c0 * 8;
  const unsigned short* gK1 = Kb + r1 * 64 + c1 * 8;
  const unsigned short* gV0 = Vb + (size_t)r0 * 2048 + c0 * 8;
  const unsigned short* gV1 = Vb + (size_t)r1 * 2048 + c1 * 8;

  uint4 pk0 = *reinterpret_cast<const uint4*>(gK0);
  uint4 pk1 = *reinterpret_cast<const uint4*>(gK1);
  uint4 pv0 = *reinterpret_cast<const uint4*>(gV0);
  uint4 pv1 = *reinterpret_cast<const uint4*>(gV1);

  float l_run = 0.f;
  f32x16 o40 = {}, o41 = {};
  const int row_lo = q5, row_hi = 32 + q5;            // A-frag rows (keys / d)
  const int swz_lo = SWZ8(row_lo), swz_hi = SWZ8(row_hi);

  for (int kt = 0; kt < 32; ++kt){
    const int cur = kt & 1;
    *reinterpret_cast<uint4*>(&Ks[cur][kof0]) = pk0;
    *reinterpret_cast<uint4*>(&Ks[cur][kof1]) = pk1;
    *reinterpret_cast<uint4*>(&Vs[cur][kof0]) = pv0;
    *reinterpret_cast<uint4*>(&Vs[cur][kof1]) = pv1;
    __syncthreads();
    if (kt < 31){
      pk0 = *reinterpret_cast<const uint4*>(gK0 + (kt + 1) * 4096);
      pk1 = *reinterpret_cast<const uint4*>(gK1 + (kt + 1) * 4096);
      pv0 = *reinterpret_cast<const uint4*>(gV0 + (kt + 1) * 64);
      pv1 = *reinterpret_cast<const uint4*>(gV1 + (kt + 1) * 64);
    }

    // QK^T: S^T = K . Q^T, two 32-key blocks, 4 k-steps of 16
    f32x16 sc0 = {}, sc1 = {};
    __builtin_amdgcn_s_setprio(1);
    #pragma unroll
    for (int ks = 0; ks < 4; ks++){
      const int ch = ks * 2 + hi;
      bf16x8 k0f = *reinterpret_cast<const bf16x8*>(&Ks[cur][row_lo * 64 + ((ch ^ swz_lo) * 8)]);
      bf16x8 k1f = *reinterpret_cast<const bf16x8*>(&Ks[cur][row_hi * 64 + ((ch ^ swz_hi) * 8)]);
      bf16x8 qk = (ks == 0) ? qf0 : (ks == 1) ? qf1 : (ks == 2) ? qf2 : qf3;
      sc0 = __builtin_amdgcn_mfma_f32_32x32x16_bf16(k0f, qk, sc0, 0, 0, 0);
      sc1 = __builtin_amdgcn_mfma_f32_32x32x16_bf16(k1f, qk, sc1, 0, 0, 0);
    }
    __builtin_amdgcn_s_setprio(0);

    // softmax: P = exp2(s) -> packed bf16 words entirely in registers
    float psum = 0.f;
    unsigned cw0[8], cw1[8];     // sc0 / sc1 words: [a0,b0,c0,d0, a1,b1,c1,d1]
    #pragma unroll
    for (int g = 0; g < 4; g++){
      float p0 = fast_exp2(sc0[4*g+0]);
      float p1 = fast_exp2(sc0[4*g+1]);
      float p2 = fast_exp2(sc0[4*g+2]);
      float p3 = fast_exp2(sc0[4*g+3]);
      psum += (p0 + p1) + (p2 + p3);
      asm("v_cvt_pk_bf16_f32 %0, %1, %2" : "=v"(cw0[2*g])   : "v"(p0), "v"(p1));
      asm("v_cvt_pk_bf16_f32 %0, %1, %2" : "=v"(cw0[2*g+1]) : "v"(p2), "v"(p3));
    }
    #pragma unroll
    for (int g = 0; g < 4; g++){
      float p0 = fast_exp2(sc1[4*g+0]);
      float p1 = fast_exp2(sc1[4*g+1]);
      float p2 = fast_exp2(sc1[4*g+2]);
      float p3 = fast_exp2(sc1[4*g+3]);
      psum += (p0 + p1) + (p2 + p3);
      asm("v_cvt_pk_bf16_f32 %0, %1, %2" : "=v"(cw1[2*g])   : "v"(p0), "v"(p1));
      asm("v_cvt_pk_bf16_f32 %0, %1, %2" : "=v"(cw1[2*g+1]) : "v"(p2), "v"(p3));
    }
    psum += __shfl_xor(psum, 32);   // complement keys live in lane l^32 (same q)
    l_run += psum;

    // build the 4 PV B-frags via permlane32_swap (2 swaps per frag)
    // swap(a, c): ret[0] = {a_lo | c_lo} = word0, ret[1] = {a_hi | c_hi} = word2
    bf16x8 pb[4];
    #pragma unroll
    for (int ks = 0; ks < 4; ks++){
      const unsigned* cw = (ks < 2) ? cw0 : cw1;
      const int base = (ks & 1) * 4;
      const unsigned a = cw[base + 0], b2 = cw[base + 1];
      const unsigned c = cw[base + 2], d = cw[base + 3];
      u32v2 s1 = __builtin_amdgcn_permlane32_swap(a, c, false, false);   // {word0, word2}
      u32v2 s2 = __builtin_amdgcn_permlane32_swap(b2, d, false, false);  // {word1, word3}
      U8 pu;
      pu.u[0] = s1[0]; pu.u[1] = s2[0]; pu.u[2] = s1[1]; pu.u[3] = s2[1];
      pb[ks] = pu.b;
    }

    // PV: O^T = V^T . P^T
    __builtin_amdgcn_s_setprio(1);
    #pragma unroll
    for (int ks = 0; ks < 4; ks++){
      const int ch = ks * 2 + hi;
      bf16x8 v0f = *reinterpret_cast<const bf16x8*>(&Vs[cur][row_lo * 64 + ((ch ^ swz_lo) * 8)]);
      bf16x8 v1f = *reinterpret_cast<const bf16x8*>(&Vs[cur][row_hi * 64 + ((ch ^ swz_hi) * 8)]);
      o40 = __builtin_amdgcn_mfma_f32_32x32x16_bf16(v0f, pb[ks], o40, 0, 0, 0);
      o41 = __builtin_amdgcn_mfma_f32_32x32x16_bf16(v1f, pb[ks], o41, 0, 0, 0);
    }
    __builtin_amdgcn_s_setprio(0);
  }

  // epilogue: normalize (denominator lane-local), restage via Ks-region scratch
  // (barrier first: other waves may still read Ks/Vs), then 16B stores.
  __syncthreads();
  uint2* Eq = reinterpret_cast<uint2*>(&Ks[0][0]) + w * 512;   // 4 KB per wave
  const float rinv = 1.f / l_run;
  const int swzp = SWZ8(q5);
  #pragma unroll
  for (int g = 0; g < 4; g++){
    float a0 = o40[4*g+0] * rinv, a1 = o40[4*g+1] * rinv;
    float a2 = o40[4*g+2] * rinv, a3 = o40[4*g+3] * rinv;
    unsigned w0, w1;
    asm("v_cvt_pk_bf16_f32 %0, %1, %2" : "=v"(w0) : "v"(a0), "v"(a1));
    asm("v_cvt_pk_bf16_f32 %0, %1, %2" : "=v"(w1) : "v"(a2), "v"(a3));
    uint2 pkv; pkv.x = w0; pkv.y = w1;
    Eq[q5 * 16 + ((g ^ swzp) * 2) + hi] = pkv;
  }
  #pragma unroll
  for (int g = 0; g < 4; g++){
    float a0 = o41[4*g+0] * rinv, a1 = o41[4*g+1] * rinv;
    float a2 = o41[4*g+2] * rinv, a3 = o41[4*g+3] * rinv;
    unsigned w0, w1;
    asm("v_cvt_pk_bf16_f32 %0, %1, %2" : "=v"(w0) : "v"(a0), "v"(a1));
    asm("v_cvt_pk_bf16_f32 %0, %1, %2" : "=v"(w1) : "v"(a2), "v"(a3));
    uint2 pkv; pkv.x = w0; pkv.y = w1;
    Eq[q5 * 16 + (((4 + g) ^ swzp) * 2) + hi] = pkv;
  }
  const int qr = l >> 1;             // 0..31: O row within wave tile
  const int cbase = (l & 1) * 4;     // chunks 0..3 / 4..7
  const int swzq = SWZ8(qr);
  const int b = bh >> 4, h = bh & 15;
  unsigned short* Ob = O + ((size_t)b * 2048 + q0 + qr) * 1024 + h * 64;
  #pragma unroll
  for (int cc = 0; cc < 4; ++cc){
    const int c = cbase + cc;
    const int base = qr * 16 + ((c ^ swzq) * 2);
    uint2 lo = Eq[base];
    uint2 hi2 = Eq[base + 1];
    uint4 xv; xv.x = lo.x; xv.y = lo.y; xv.z = hi2.x; xv.w = hi2.y;
    *reinterpret_cast<uint4*>(Ob + c * 8) = xv;
  }
}

extern "C" void kernel_launch(void* const* d_in, const int* in_sizes, int n_in,
                              void* d_out, int out_size, void* d_ws, size_t ws_size,
                              hipStream_t stream){
  const float* query = (const float*)d_in[0];
  const float* Wqkv  = (const float*)d_in[1];
  const float* bqkv  = (const float*)d_in[2];
  const float* Wout  = (const float*)d_in[3];
  const float* bout  = (const float*)d_in[4];
  float* out = (float*)d_out;

  unsigned short* ws    = (unsigned short*)d_ws;
  unsigned short* xbf   = ws;                      // 4096x1024 (query bf16; dead after gemm<0> -> attn out)
  unsigned short* wqkvT = xbf   + 4194304;         // 3072x1024
  unsigned short* woutT = wqkvT + 3145728;         // 1024x1024
  unsigned short* qbf   = woutT + 1048576;         // [32][2048][64]
  unsigned short* kbf   = qbf   + 4194304;         // [32][2048][64]
  unsigned short* vtbf  = kbf   + 4194304;         // [32][64][2048]
  unsigned short* abf   = xbf;                     // attn out aliases dead xbf

  prep<<<3072, 256, 0, stream>>>(query, Wqkv, Wout, xbf, wqkvT, woutT);
  gemm_bt<0><<<dim3(24, 32), 256, 0, stream>>>(xbf, wqkvT, bqkv, qbf, kbf, vtbf, nullptr);
  attn_fwd<<<dim3(16, 32), 256, 0, stream>>>(qbf, kbf, vtbf, abf);
  gemm_bt<1><<<dim3(16, 32), 256, 0, stream>>>(abf, woutT, bout, nullptr, nullptr, nullptr, out);
}

// Round 19
// 126.933 us; speedup vs baseline: 1.1174x; 1.1174x over previous
//
#include <hip/hip_runtime.h>
#include <stdint.h>

typedef __attribute__((ext_vector_type(4))) float f32x4;
typedef __attribute__((ext_vector_type(16))) float f32x16;
typedef __attribute__((ext_vector_type(8))) __bf16 bf16x8;
typedef __attribute__((ext_vector_type(2))) unsigned int u32v2;

#define GLDS(g, s) __builtin_amdgcn_global_load_lds( \
    (const __attribute__((address_space(1))) void*)(g), \
    (__attribute__((address_space(3))) void*)(s), 16, 0, 0)

// row-aware LDS chunk swizzle: distinct for rows 8 apart
#define SWZ8(r) ((((r) ^ ((r) >> 3))) & 7)

__device__ inline float fast_exp2(float x){
#if __has_builtin(__builtin_amdgcn_exp2f)
  return __builtin_amdgcn_exp2f(x);
#else
  float r; asm("v_exp_f32 %0, %1" : "=v"(r) : "v"(x)); return r;
#endif
}

__device__ inline unsigned short f2bf(float f){
  union { float f; unsigned int u; } v; v.f = f;
  unsigned int u = v.u;
  unsigned int r = (u + 0x7fffu + ((u >> 16) & 1u)) >> 16;
  return (unsigned short)r;
}

// ---------------- prep: fp32->bf16 cvt (blocks 0..2047) + both W transposes (2048..3071) ----------------
__global__ __launch_bounds__(256) void prep(const float* __restrict__ x,
                                            const float* __restrict__ Wqkv,
                                            const float* __restrict__ Wout,
                                            unsigned short* __restrict__ y,
                                            unsigned short* __restrict__ wqkvT,
                                            unsigned short* __restrict__ woutT){
  __shared__ float tile[64][65];
  const int bx = blockIdx.x;
  const int t = threadIdx.x;
  if (bx < 2048){
    const size_t i = ((size_t)bx * 256 + t) * 8;
    float4 a = *reinterpret_cast<const float4*>(x + i);
    float4 b = *reinterpret_cast<const float4*>(x + i + 4);
    uint4 o;
    o.x = (unsigned)f2bf(a.x) | ((unsigned)f2bf(a.y) << 16);
    o.y = (unsigned)f2bf(a.z) | ((unsigned)f2bf(a.w) << 16);
    o.z = (unsigned)f2bf(b.x) | ((unsigned)f2bf(b.y) << 16);
    o.w = (unsigned)f2bf(b.z) | ((unsigned)f2bf(b.w) << 16);
    *reinterpret_cast<uint4*>(y + i) = o;
    return;
  }
  const int tb = bx - 2048;           // [0,1024): 64 n-blocks x 16 k-blocks
  const int nb = tb & 63;
  const int k0 = (tb >> 6) * 64;
  const float* W; unsigned short* WT; int N, n0;
  if (nb < 48){ W = Wqkv; WT = wqkvT; N = 3072; n0 = nb * 64; }
  else        { W = Wout; WT = woutT; N = 1024; n0 = (nb - 48) * 64; }
  #pragma unroll
  for (int p = 0; p < 16; p++){
    int idx = p * 256 + t; int r = idx >> 6, c = idx & 63;
    tile[r][c] = W[(size_t)(k0 + r) * N + n0 + c];
  }
  __syncthreads();
  #pragma unroll
  for (int p = 0; p < 16; p++){
    int idx = p * 256 + t; int r = idx >> 6, c = idx & 63;
    WT[(size_t)(n0 + r) * 1024 + k0 + c] = f2bf(tile[c][r]);
  }
}

// ---------------- GEMM (round-16 core; ONE change: s_setprio removed -- m190:
// setprio hurts barrier-lockstep multi-wave GEMM) ----------------
template<int MODE>
__global__ __launch_bounds__(256) void gemm_bt(
    const unsigned short* __restrict__ X,
    const unsigned short* __restrict__ WT,
    const float* __restrict__ bias,
    unsigned short* __restrict__ oq,
    unsigned short* __restrict__ ok,
    unsigned short* __restrict__ ovt,   // [BH][64][S] (V transposed), MODE 0 only
    float* __restrict__ ofp)
{
  constexpr int Kdim = 1024;
  constexpr int BN = (MODE == 0) ? 128 : 64;
  constexpr int JN = (MODE == 0) ? 4 : 2;     // n-frags per wave
  __shared__ __align__(16) unsigned short As[128 * 32];
  __shared__ __align__(16) unsigned short Bs[BN * 32];
  const int t  = threadIdx.x;
  const int l  = t & 63;
  const int w  = t >> 6;
  const int lr = l & 15, lg = l >> 4;
  const int wr = w >> 1, wc = w & 1;

  // XCD-chunked bijective swizzle (nwg = 768 / 512, both % 8 == 0)
  const unsigned nx = gridDim.x;
  const unsigned nwg = nx * gridDim.y;
  const unsigned f0 = blockIdx.y * nx + blockIdx.x;
  const unsigned f  = (f0 & 7) * (nwg >> 3) + (f0 >> 3);
  const int m0 = (int)(f / nx) * 128;
  const int n0 = (int)(f % nx) * BN;

  const int lrow = l >> 2;
  const int lch  = (l & 3) * 8;
  const unsigned short* gA0 = X  + (size_t)(m0 + w * 16 + lrow) * Kdim + lch;
  const unsigned short* gA1 = gA0 + (size_t)64 * Kdim;
  const unsigned short* gB0 = WT + (size_t)(n0 + w * 16 + lrow) * Kdim + lch;
  unsigned short* lA0 = &As[(w * 16) * 32];
  unsigned short* lA1 = &As[(64 + w * 16) * 32];
  unsigned short* lB0 = &Bs[(w * 16) * 32];

  f32x4 zero4 = {0.f, 0.f, 0.f, 0.f};
  f32x4 acc[4][JN];
  #pragma unroll
  for (int i = 0; i < 4; i++)
    #pragma unroll
    for (int j = 0; j < JN; j++) acc[i][j] = zero4;

  const int aoff = (wr * 64 + lr) * 32 + lg * 8;
  const int boff = (wc * (BN / 2) + lr) * 32 + lg * 8;

  for (int kt = 0; kt < Kdim / 32; ++kt){
    const int kb = kt * 32;
    __syncthreads();
    GLDS(gA0 + kb, lA0);
    GLDS(gA1 + kb, lA1);
    GLDS(gB0 + kb, lB0);
    if constexpr (MODE == 0){
      const unsigned short* gB1 = gB0 + (size_t)64 * Kdim;
      GLDS(gB1 + kb, &Bs[(64 + w * 16) * 32]);
    }
    __syncthreads();
    bf16x8 af[4], bfr[JN];
    #pragma unroll
    for (int i = 0; i < 4; i++)  af[i]  = *reinterpret_cast<const bf16x8*>(&As[aoff + i * 16 * 32]);
    #pragma unroll
    for (int j = 0; j < JN; j++) bfr[j] = *reinterpret_cast<const bf16x8*>(&Bs[boff + j * 16 * 32]);
    #pragma unroll
    for (int i = 0; i < 4; i++)
      #pragma unroll
      for (int j = 0; j < JN; j++)
        acc[i][j] = __builtin_amdgcn_mfma_f32_16x16x32_bf16(af[i], bfr[j], acc[i][j], 0, 0, 0);
  }

  const int mbg = m0 + wr * 64;               // wave's global m-base (64-aligned)
  const int nb  = n0 + wc * (BN / 2);         // wave's global n-base
  if constexpr (MODE == 0){
    __shared__ __align__(16) unsigned short Ep[4][64 * 72];
    unsigned short* E = Ep[w];
    const int which = n0 >> 10;               // 0=Q,1=K,2=V (128-tile wholly inside one)
    const int h = (nb >> 6) & 15;             // wave-uniform head
    const float qs = (which == 0) ? 0.18033688011f : 1.0f;   // 0.125*log2(e)
    #pragma unroll
    for (int j = 0; j < 4; j++){
      const float bs = bias[nb + j * 16 + lr];
      const int nloc = j * 16 + lr;
      #pragma unroll
      for (int i = 0; i < 4; i++){
        #pragma unroll
        for (int r = 0; r < 4; r++){
          const int mloc = i * 16 + 4 * lg + r;
          const unsigned short vv = f2bf((acc[i][j][r] + bs) * qs);
          if (which == 2) E[nloc * 72 + mloc] = vv;   // [d][s] -> V pre-transposed
          else            E[mloc * 72 + nloc] = vv;   // [s][d]
        }
      }
    }
    asm volatile("s_waitcnt lgkmcnt(0)" ::: "memory");
    __builtin_amdgcn_sched_barrier(0);
    const int b = mbg >> 11, sib = mbg & 2047;
    const size_t bh = (size_t)(b * 16 + h);
    if (which == 2){
      unsigned short* dst = ovt + bh * 64 * 2048 + sib;
      #pragma unroll
      for (int it = 0; it < 8; ++it){
        const int d = it * 8 + (l >> 3);
        const int sc8 = (l & 7) * 8;
        uint4 xv = *reinterpret_cast<const uint4*>(&E[d * 72 + sc8]);
        *reinterpret_cast<uint4*>(dst + (size_t)d * 2048 + sc8) = xv;
      }
    } else {
      unsigned short* dst = (which == 0 ? oq : ok) + (bh * 2048 + sib) * 64;
      #pragma unroll
      for (int it = 0; it < 8; ++it){
        const int sl = it * 8 + (l >> 3);
        const int dc8 = (l & 7) * 8;
        uint4 xv = *reinterpret_cast<const uint4*>(&E[sl * 72 + dc8]);
        *reinterpret_cast<uint4*>(dst + (size_t)sl * 64 + dc8) = xv;
      }
    }
  } else {
    __shared__ __align__(16) float Epf[4][64 * 36];
    float* E = Epf[w];
    #pragma unroll
    for (int j = 0; j < JN; j++){
      const float bs = bias[nb + j * 16 + lr];
      const int nloc = j * 16 + lr;
      #pragma unroll
      for (int i = 0; i < 4; i++){
        #pragma unroll
        for (int r = 0; r < 4; r++){
          const int mloc = i * 16 + 4 * lg + r;
          E[mloc * 36 + nloc] = acc[i][j][r] + bs;
        }
      }
    }
    asm volatile("s_waitcnt lgkmcnt(0)" ::: "memory");
    __builtin_amdgcn_sched_barrier(0);
    #pragma unroll
    for (int it = 0; it < 8; ++it){
      const int ml = it * 8 + (l >> 3);
      const int nc = (l & 7) * 4;
      uint4 xv = *reinterpret_cast<const uint4*>(&E[ml * 36 + nc]);
      *reinterpret_cast<uint4*>(ofp + (size_t)(mbg + ml) * 1024 + nb + nc) = xv;
    }
  }
}

// ---------------- Flash attention fwd (round-16-verified, verbatim) ----------------
// 32x32x16, 32 q/wave, in-register P via cvt_pk + permlane32_swap; reg-staged
// K/V prefetch (T14: loads stay in flight across the barrier).
__global__ __launch_bounds__(256) void attn_fwd(
    const unsigned short* __restrict__ Q,   // [BH][S][64]
    const unsigned short* __restrict__ Kt,  // [BH][S][64]
    const unsigned short* __restrict__ VT,  // [BH][64][S]
    unsigned short* __restrict__ O)         // [B][S][1024]
{
  __shared__ __align__(16) unsigned short Ks[2][4096];
  __shared__ __align__(16) unsigned short Vs[2][4096];
  const int t = threadIdx.x;
  const int l = t & 63, w = t >> 6;
  const int q5 = l & 31;          // lane's q (B/D col) -- also key/d row for A-frags
  const int hi = l >> 5;          // k-group selector

  const unsigned flat = blockIdx.y * gridDim.x + blockIdx.x;   // 512 wgs
  const unsigned fl = (flat & 7) * 64 + (flat >> 3);           // XCD-chunked (bijective)
  const int bh = fl >> 4;
  const int q0 = (fl & 15) * 128 + w * 32;

  const unsigned short* Qb = Q + ((size_t)bh * 2048 + q0) * 64;
  bf16x8 qf0 = *reinterpret_cast<const bf16x8*>(Qb + (size_t)q5 * 64 +  0 + hi * 8);
  bf16x8 qf1 = *reinterpret_cast<const bf16x8*>(Qb + (size_t)q5 * 64 + 16 + hi * 8);
  bf16x8 qf2 = *reinterpret_cast<const bf16x8*>(Qb + (size_t)q5 * 64 + 32 + hi * 8);
  bf16x8 qf3 = *reinterpret_cast<const bf16x8*>(Qb + (size_t)q5 * 64 + 48 + hi * 8);
  const unsigned short* Kb = Kt + (size_t)bh * 2048 * 64;
  const unsigned short* Vb = VT + (size_t)bh * 64 * 2048;

  union U8 { unsigned u[4]; uint4 u4; bf16x8 b; };

  // staging map: thread t -> (row r, 16B chunk c); SWZ'd LDS dest
  const int r0 = t >> 3,        c0 = t & 7;
  const int r1 = 32 + (t >> 3), c1 = t & 7;
  const int kof0 = r0 * 64 + ((c0 ^ SWZ8(r0)) * 8);
  const int kof1 = r1 * 64 + ((c1 ^ SWZ8(r1)) * 8);
  const unsigned short* gK0 = Kb + r0 * 64 + c0 * 8;
  const unsigned short* gK1 = Kb + r1 * 64 + c1 * 8;
  const unsigned short* gV0 = Vb + (size_t)r0 * 2048 + c0 * 8;
  const unsigned short* gV1 = Vb + (size_t)r1 * 2048 + c1 * 8;

  uint4 pk0 = *reinterpret_cast<const uint4*>(gK0);
  uint4 pk1 = *reinterpret_cast<const uint4*>(gK1);
  uint4 pv0 = *reinterpret_cast<const uint4*>(gV0);
  uint4 pv1 = *reinterpret_cast<const uint4*>(gV1);

  float l_run = 0.f;
  f32x16 o40 = {}, o41 = {};
  const int row_lo = q5, row_hi = 32 + q5;            // A-frag rows (keys / d)
  const int swz_lo = SWZ8(row_lo), swz_hi = SWZ8(row_hi);

  for (int kt = 0; kt < 32; ++kt){
    const int cur = kt & 1;
    *reinterpret_cast<uint4*>(&Ks[cur][kof0]) = pk0;
    *reinterpret_cast<uint4*>(&Ks[cur][kof1]) = pk1;
    *reinterpret_cast<uint4*>(&Vs[cur][kof0]) = pv0;
    *reinterpret_cast<uint4*>(&Vs[cur][kof1]) = pv1;
    __syncthreads();
    if (kt < 31){
      pk0 = *reinterpret_cast<const uint4*>(gK0 + (kt + 1) * 4096);
      pk1 = *reinterpret_cast<const uint4*>(gK1 + (kt + 1) * 4096);
      pv0 = *reinterpret_cast<const uint4*>(gV0 + (kt + 1) * 64);
      pv1 = *reinterpret_cast<const uint4*>(gV1 + (kt + 1) * 64);
    }

    // QK^T: S^T = K . Q^T, two 32-key blocks, 4 k-steps of 16
    f32x16 sc0 = {}, sc1 = {};
    __builtin_amdgcn_s_setprio(1);
    #pragma unroll
    for (int ks = 0; ks < 4; ks++){
      const int ch = ks * 2 + hi;
      bf16x8 k0f = *reinterpret_cast<const bf16x8*>(&Ks[cur][row_lo * 64 + ((ch ^ swz_lo) * 8)]);
      bf16x8 k1f = *reinterpret_cast<const bf16x8*>(&Ks[cur][row_hi * 64 + ((ch ^ swz_hi) * 8)]);
      bf16x8 qk = (ks == 0) ? qf0 : (ks == 1) ? qf1 : (ks == 2) ? qf2 : qf3;
      sc0 = __builtin_amdgcn_mfma_f32_32x32x16_bf16(k0f, qk, sc0, 0, 0, 0);
      sc1 = __builtin_amdgcn_mfma_f32_32x32x16_bf16(k1f, qk, sc1, 0, 0, 0);
    }
    __builtin_amdgcn_s_setprio(0);

    // softmax: P = exp2(s) -> packed bf16 words entirely in registers
    float psum = 0.f;
    unsigned cw0[8], cw1[8];     // sc0 / sc1 words: [a0,b0,c0,d0, a1,b1,c1,d1]
    #pragma unroll
    for (int g = 0; g < 4; g++){
      float p0 = fast_exp2(sc0[4*g+0]);
      float p1 = fast_exp2(sc0[4*g+1]);
      float p2 = fast_exp2(sc0[4*g+2]);
      float p3 = fast_exp2(sc0[4*g+3]);
      psum += (p0 + p1) + (p2 + p3);
      asm("v_cvt_pk_bf16_f32 %0, %1, %2" : "=v"(cw0[2*g])   : "v"(p0), "v"(p1));
      asm("v_cvt_pk_bf16_f32 %0, %1, %2" : "=v"(cw0[2*g+1]) : "v"(p2), "v"(p3));
    }
    #pragma unroll
    for (int g = 0; g < 4; g++){
      float p0 = fast_exp2(sc1[4*g+0]);
      float p1 = fast_exp2(sc1[4*g+1]);
      float p2 = fast_exp2(sc1[4*g+2]);
      float p3 = fast_exp2(sc1[4*g+3]);
      psum += (p0 + p1) + (p2 + p3);
      asm("v_cvt_pk_bf16_f32 %0, %1, %2" : "=v"(cw1[2*g])   : "v"(p0), "v"(p1));
      asm("v_cvt_pk_bf16_f32 %0, %1, %2" : "=v"(cw1[2*g+1]) : "v"(p2), "v"(p3));
    }
    psum += __shfl_xor(psum, 32);   // complement keys live in lane l^32 (same q)
    l_run += psum;

    // build the 4 PV B-frags via permlane32_swap (2 swaps per frag)
    // swap(a, c): ret[0] = {a_lo | c_lo} = word0, ret[1] = {a_hi | c_hi} = word2
    bf16x8 pb[4];
    #pragma unroll
    for (int ks = 0; ks < 4; ks++){
      const unsigned* cw = (ks < 2) ? cw0 : cw1;
      const int base = (ks & 1) * 4;
      const unsigned a = cw[base + 0], b2 = cw[base + 1];
      const unsigned c = cw[base + 2], d = cw[base + 3];
      u32v2 s1 = __builtin_amdgcn_permlane32_swap(a, c, false, false);   // {word0, word2}
      u32v2 s2 = __builtin_amdgcn_permlane32_swap(b2, d, false, false);  // {word1, word3}
      U8 pu;
      pu.u[0] = s1[0]; pu.u[1] = s2[0]; pu.u[2] = s1[1]; pu.u[3] = s2[1];
      pb[ks] = pu.b;
    }

    // PV: O^T = V^T . P^T
    __builtin_amdgcn_s_setprio(1);
    #pragma unroll
    for (int ks = 0; ks < 4; ks++){
      const int ch = ks * 2 + hi;
      bf16x8 v0f = *reinterpret_cast<const bf16x8*>(&Vs[cur][row_lo * 64 + ((ch ^ swz_lo) * 8)]);
      bf16x8 v1f = *reinterpret_cast<const bf16x8*>(&Vs[cur][row_hi * 64 + ((ch ^ swz_hi) * 8)]);
      o40 = __builtin_amdgcn_mfma_f32_32x32x16_bf16(v0f, pb[ks], o40, 0, 0, 0);
      o41 = __builtin_amdgcn_mfma_f32_32x32x16_bf16(v1f, pb[ks], o41, 0, 0, 0);
    }
    __builtin_amdgcn_s_setprio(0);
  }

  // epilogue: normalize (denominator lane-local), restage via Ks-region scratch
  // (barrier first: other waves may still read Ks/Vs), then 16B stores.
  __syncthreads();
  uint2* Eq = reinterpret_cast<uint2*>(&Ks[0][0]) + w * 512;   // 4 KB per wave
  const float rinv = 1.f / l_run;
  const int swzp = SWZ8(q5);
  #pragma unroll
  for (int g = 0; g < 4; g++){
    float a0 = o40[4*g+0] * rinv, a1 = o40[4*g+1] * rinv;
    float a2 = o40[4*g+2] * rinv, a3 = o40[4*g+3] * rinv;
    unsigned w0, w1;
    asm("v_cvt_pk_bf16_f32 %0, %1, %2" : "=v"(w0) : "v"(a0), "v"(a1));
    asm("v_cvt_pk_bf16_f32 %0, %1, %2" : "=v"(w1) : "v"(a2), "v"(a3));
    uint2 pkv; pkv.x = w0; pkv.y = w1;
    Eq[q5 * 16 + ((g ^ swzp) * 2) + hi] = pkv;
  }
  #pragma unroll
  for (int g = 0; g < 4; g++){
    float a0 = o41[4*g+0] * rinv, a1 = o41[4*g+1] * rinv;
    float a2 = o41[4*g+2] * rinv, a3 = o41[4*g+3] * rinv;
    unsigned w0, w1;
    asm("v_cvt_pk_bf16_f32 %0, %1, %2" : "=v"(w0) : "v"(a0), "v"(a1));
    asm("v_cvt_pk_bf16_f32 %0, %1, %2" : "=v"(w1) : "v"(a2), "v"(a3));
    uint2 pkv; pkv.x = w0; pkv.y = w1;
    Eq[q5 * 16 + (((4 + g) ^ swzp) * 2) + hi] = pkv;
  }
  const int qr = l >> 1;             // 0..31: O row within wave tile
  const int cbase = (l & 1) * 4;     // chunks 0..3 / 4..7
  const int swzq = SWZ8(qr);
  const int b = bh >> 4, h = bh & 15;
  unsigned short* Ob = O + ((size_t)b * 2048 + q0 + qr) * 1024 + h * 64;
  #pragma unroll
  for (int cc = 0; cc < 4; ++cc){
    const int c = cbase + cc;
    const int base = qr * 16 + ((c ^ swzq) * 2);
    uint2 lo = Eq[base];
    uint2 hi2 = Eq[base + 1];
    uint4 xv; xv.x = lo.x; xv.y = lo.y; xv.z = hi2.x; xv.w = hi2.y;
    *reinterpret_cast<uint4*>(Ob + c * 8) = xv;
  }
}

extern "C" void kernel_launch(void* const* d_in, const int* in_sizes, int n_in,
                              void* d_out, int out_size, void* d_ws, size_t ws_size,
                              hipStream_t stream){
  const float* query = (const float*)d_in[0];
  const float* Wqkv  = (const float*)d_in[1];
  const float* bqkv  = (const float*)d_in[2];
  const float* Wout  = (const float*)d_in[3];
  const float* bout  = (const float*)d_in[4];
  float* out = (float*)d_out;

  unsigned short* ws    = (unsigned short*)d_ws;
  unsigned short* xbf   = ws;                      // 4096x1024 (query bf16; dead after gemm<0> -> attn out)
  unsigned short* wqkvT = xbf   + 4194304;         // 3072x1024
  unsigned short* woutT = wqkvT + 3145728;         // 1024x1024
  unsigned short* qbf   = woutT + 1048576;         // [32][2048][64]
  unsigned short* kbf   = qbf   + 4194304;         // [32][2048][64]
  unsigned short* vtbf  = kbf   + 4194304;         // [32][64][2048]
  unsigned short* abf   = xbf;                     // attn out aliases dead xbf

  prep<<<3072, 256, 0, stream>>>(query, Wqkv, Wout, xbf, wqkvT, woutT);
  gemm_bt<0><<<dim3(24, 32), 256, 0, stream>>>(xbf, wqkvT, bqkv, qbf, kbf, vtbf, nullptr);
  attn_fwd<<<dim3(16, 32), 256, 0, stream>>>(qbf, kbf, vtbf, abf);
  gemm_bt<1><<<dim3(16, 32), 256, 0, stream>>>(abf, woutT, bout, nullptr, nullptr, nullptr, out);
}

// Round 20
// 126.245 us; speedup vs baseline: 1.1235x; 1.0055x over previous
//
#include <hip/hip_runtime.h>
#include <stdint.h>

typedef __attribute__((ext_vector_type(4))) float f32x4;
typedef __attribute__((ext_vector_type(16))) float f32x16;
typedef __attribute__((ext_vector_type(8))) __bf16 bf16x8;
typedef __attribute__((ext_vector_type(2))) unsigned int u32v2;

#define GLDS(g, s) __builtin_amdgcn_global_load_lds( \
    (const __attribute__((address_space(1))) void*)(g), \
    (__attribute__((address_space(3))) void*)(s), 16, 0, 0)

// row-aware LDS chunk swizzle: distinct for rows 8 apart
#define SWZ8(r) ((((r) ^ ((r) >> 3))) & 7)

__device__ inline float fast_exp2(float x){
#if __has_builtin(__builtin_amdgcn_exp2f)
  return __builtin_amdgcn_exp2f(x);
#else
  float r; asm("v_exp_f32 %0, %1" : "=v"(r) : "v"(x)); return r;
#endif
}

__device__ inline unsigned short f2bf(float f){
  union { float f; unsigned int u; } v; v.f = f;
  unsigned int u = v.u;
  unsigned int r = (u + 0x7fffu + ((u >> 16) & 1u)) >> 16;
  return (unsigned short)r;
}

// ---------------- prep: fp32->bf16 cvt (blocks 0..2047) + both W transposes (2048..3071) ----------------
__global__ __launch_bounds__(256) void prep(const float* __restrict__ x,
                                            const float* __restrict__ Wqkv,
                                            const float* __restrict__ Wout,
                                            unsigned short* __restrict__ y,
                                            unsigned short* __restrict__ wqkvT,
                                            unsigned short* __restrict__ woutT){
  __shared__ float tile[64][65];
  const int bx = blockIdx.x;
  const int t = threadIdx.x;
  if (bx < 2048){
    const size_t i = ((size_t)bx * 256 + t) * 8;
    float4 a = *reinterpret_cast<const float4*>(x + i);
    float4 b = *reinterpret_cast<const float4*>(x + i + 4);
    uint4 o;
    o.x = (unsigned)f2bf(a.x) | ((unsigned)f2bf(a.y) << 16);
    o.y = (unsigned)f2bf(a.z) | ((unsigned)f2bf(a.w) << 16);
    o.z = (unsigned)f2bf(b.x) | ((unsigned)f2bf(b.y) << 16);
    o.w = (unsigned)f2bf(b.z) | ((unsigned)f2bf(b.w) << 16);
    *reinterpret_cast<uint4*>(y + i) = o;
    return;
  }
  const int tb = bx - 2048;           // [0,1024): 64 n-blocks x 16 k-blocks
  const int nb = tb & 63;
  const int k0 = (tb >> 6) * 64;
  const float* W; unsigned short* WT; int N, n0;
  if (nb < 48){ W = Wqkv; WT = wqkvT; N = 3072; n0 = nb * 64; }
  else        { W = Wout; WT = woutT; N = 1024; n0 = (nb - 48) * 64; }
  #pragma unroll
  for (int p = 0; p < 16; p++){
    int idx = p * 256 + t; int r = idx >> 6, c = idx & 63;
    tile[r][c] = W[(size_t)(k0 + r) * N + n0 + c];
  }
  __syncthreads();
  #pragma unroll
  for (int p = 0; p < 16; p++){
    int idx = p * 256 + t; int r = idx >> 6, c = idx & 63;
    WT[(size_t)(n0 + r) * 1024 + k0 + c] = f2bf(tile[c][r]);
  }
}

// ---------------- GEMM (round-19-verified: no setprio, XCD swizzle, LDS re-tile epilogues) ----------------
template<int MODE>
__global__ __launch_bounds__(256) void gemm_bt(
    const unsigned short* __restrict__ X,
    const unsigned short* __restrict__ WT,
    const float* __restrict__ bias,
    unsigned short* __restrict__ oq,
    unsigned short* __restrict__ ok,
    unsigned short* __restrict__ ovt,   // [BH][64][S] (V transposed), MODE 0 only
    float* __restrict__ ofp)
{
  constexpr int Kdim = 1024;
  constexpr int BN = (MODE == 0) ? 128 : 64;
  constexpr int JN = (MODE == 0) ? 4 : 2;     // n-frags per wave
  __shared__ __align__(16) unsigned short As[128 * 32];
  __shared__ __align__(16) unsigned short Bs[BN * 32];
  const int t  = threadIdx.x;
  const int l  = t & 63;
  const int w  = t >> 6;
  const int lr = l & 15, lg = l >> 4;
  const int wr = w >> 1, wc = w & 1;

  // XCD-chunked bijective swizzle (nwg = 768 / 512, both % 8 == 0)
  const unsigned nx = gridDim.x;
  const unsigned nwg = nx * gridDim.y;
  const unsigned f0 = blockIdx.y * nx + blockIdx.x;
  const unsigned f  = (f0 & 7) * (nwg >> 3) + (f0 >> 3);
  const int m0 = (int)(f / nx) * 128;
  const int n0 = (int)(f % nx) * BN;

  const int lrow = l >> 2;
  const int lch  = (l & 3) * 8;
  const unsigned short* gA0 = X  + (size_t)(m0 + w * 16 + lrow) * Kdim + lch;
  const unsigned short* gA1 = gA0 + (size_t)64 * Kdim;
  const unsigned short* gB0 = WT + (size_t)(n0 + w * 16 + lrow) * Kdim + lch;
  unsigned short* lA0 = &As[(w * 16) * 32];
  unsigned short* lA1 = &As[(64 + w * 16) * 32];
  unsigned short* lB0 = &Bs[(w * 16) * 32];

  f32x4 zero4 = {0.f, 0.f, 0.f, 0.f};
  f32x4 acc[4][JN];
  #pragma unroll
  for (int i = 0; i < 4; i++)
    #pragma unroll
    for (int j = 0; j < JN; j++) acc[i][j] = zero4;

  const int aoff = (wr * 64 + lr) * 32 + lg * 8;
  const int boff = (wc * (BN / 2) + lr) * 32 + lg * 8;

  for (int kt = 0; kt < Kdim / 32; ++kt){
    const int kb = kt * 32;
    __syncthreads();
    GLDS(gA0 + kb, lA0);
    GLDS(gA1 + kb, lA1);
    GLDS(gB0 + kb, lB0);
    if constexpr (MODE == 0){
      const unsigned short* gB1 = gB0 + (size_t)64 * Kdim;
      GLDS(gB1 + kb, &Bs[(64 + w * 16) * 32]);
    }
    __syncthreads();
    bf16x8 af[4], bfr[JN];
    #pragma unroll
    for (int i = 0; i < 4; i++)  af[i]  = *reinterpret_cast<const bf16x8*>(&As[aoff + i * 16 * 32]);
    #pragma unroll
    for (int j = 0; j < JN; j++) bfr[j] = *reinterpret_cast<const bf16x8*>(&Bs[boff + j * 16 * 32]);
    #pragma unroll
    for (int i = 0; i < 4; i++)
      #pragma unroll
      for (int j = 0; j < JN; j++)
        acc[i][j] = __builtin_amdgcn_mfma_f32_16x16x32_bf16(af[i], bfr[j], acc[i][j], 0, 0, 0);
  }

  const int mbg = m0 + wr * 64;               // wave's global m-base (64-aligned)
  const int nb  = n0 + wc * (BN / 2);         // wave's global n-base
  if constexpr (MODE == 0){
    __shared__ __align__(16) unsigned short Ep[4][64 * 72];
    unsigned short* E = Ep[w];
    const int which = n0 >> 10;               // 0=Q,1=K,2=V (128-tile wholly inside one)
    const int h = (nb >> 6) & 15;             // wave-uniform head
    const float qs = (which == 0) ? 0.18033688011f : 1.0f;   // 0.125*log2(e)
    #pragma unroll
    for (int j = 0; j < 4; j++){
      const float bs = bias[nb + j * 16 + lr];
      const int nloc = j * 16 + lr;
      #pragma unroll
      for (int i = 0; i < 4; i++){
        #pragma unroll
        for (int r = 0; r < 4; r++){
          const int mloc = i * 16 + 4 * lg + r;
          const unsigned short vv = f2bf((acc[i][j][r] + bs) * qs);
          if (which == 2) E[nloc * 72 + mloc] = vv;   // [d][s] -> V pre-transposed
          else            E[mloc * 72 + nloc] = vv;   // [s][d]
        }
      }
    }
    asm volatile("s_waitcnt lgkmcnt(0)" ::: "memory");
    __builtin_amdgcn_sched_barrier(0);
    const int b = mbg >> 11, sib = mbg & 2047;
    const size_t bh = (size_t)(b * 16 + h);
    if (which == 2){
      unsigned short* dst = ovt + bh * 64 * 2048 + sib;
      #pragma unroll
      for (int it = 0; it < 8; ++it){
        const int d = it * 8 + (l >> 3);
        const int sc8 = (l & 7) * 8;
        uint4 xv = *reinterpret_cast<const uint4*>(&E[d * 72 + sc8]);
        *reinterpret_cast<uint4*>(dst + (size_t)d * 2048 + sc8) = xv;
      }
    } else {
      unsigned short* dst = (which == 0 ? oq : ok) + (bh * 2048 + sib) * 64;
      #pragma unroll
      for (int it = 0; it < 8; ++it){
        const int sl = it * 8 + (l >> 3);
        const int dc8 = (l & 7) * 8;
        uint4 xv = *reinterpret_cast<const uint4*>(&E[sl * 72 + dc8]);
        *reinterpret_cast<uint4*>(dst + (size_t)sl * 64 + dc8) = xv;
      }
    }
  } else {
    __shared__ __align__(16) float Epf[4][64 * 36];
    float* E = Epf[w];
    #pragma unroll
    for (int j = 0; j < JN; j++){
      const float bs = bias[nb + j * 16 + lr];
      const int nloc = j * 16 + lr;
      #pragma unroll
      for (int i = 0; i < 4; i++){
        #pragma unroll
        for (int r = 0; r < 4; r++){
          const int mloc = i * 16 + 4 * lg + r;
          E[mloc * 36 + nloc] = acc[i][j][r] + bs;
        }
      }
    }
    asm volatile("s_waitcnt lgkmcnt(0)" ::: "memory");
    __builtin_amdgcn_sched_barrier(0);
    #pragma unroll
    for (int it = 0; it < 8; ++it){
      const int ml = it * 8 + (l >> 3);
      const int nc = (l & 7) * 4;
      uint4 xv = *reinterpret_cast<const uint4*>(&E[ml * 36 + nc]);
      *reinterpret_cast<uint4*>(ofp + (size_t)(mbg + ml) * 1024 + nb + nc) = xv;
    }
  }
}

// ---------------- Flash attention fwd (round-16/19 body; ONE change: setprio removed ----
// -- m190: setprio hurts barrier-lockstep multi-wave kernels, and this attn is
// 4-wave lockstep; round 19 confirmed the win on the GEMMs) ----------------
__global__ __launch_bounds__(256) void attn_fwd(
    const unsigned short* __restrict__ Q,   // [BH][S][64]
    const unsigned short* __restrict__ Kt,  // [BH][S][64]
    const unsigned short* __restrict__ VT,  // [BH][64][S]
    unsigned short* __restrict__ O)         // [B][S][1024]
{
  __shared__ __align__(16) unsigned short Ks[2][4096];
  __shared__ __align__(16) unsigned short Vs[2][4096];
  const int t = threadIdx.x;
  const int l = t & 63, w = t >> 6;
  const int q5 = l & 31;          // lane's q (B/D col) -- also key/d row for A-frags
  const int hi = l >> 5;          // k-group selector

  const unsigned flat = blockIdx.y * gridDim.x + blockIdx.x;   // 512 wgs
  const unsigned fl = (flat & 7) * 64 + (flat >> 3);           // XCD-chunked (bijective)
  const int bh = fl >> 4;
  const int q0 = (fl & 15) * 128 + w * 32;

  const unsigned short* Qb = Q + ((size_t)bh * 2048 + q0) * 64;
  bf16x8 qf0 = *reinterpret_cast<const bf16x8*>(Qb + (size_t)q5 * 64 +  0 + hi * 8);
  bf16x8 qf1 = *reinterpret_cast<const bf16x8*>(Qb + (size_t)q5 * 64 + 16 + hi * 8);
  bf16x8 qf2 = *reinterpret_cast<const bf16x8*>(Qb + (size_t)q5 * 64 + 32 + hi * 8);
  bf16x8 qf3 = *reinterpret_cast<const bf16x8*>(Qb + (size_t)q5 * 64 + 48 + hi * 8);
  const unsigned short* Kb = Kt + (size_t)bh * 2048 * 64;
  const unsigned short* Vb = VT + (size_t)bh * 64 * 2048;

  union U8 { unsigned u[4]; uint4 u4; bf16x8 b; };

  // staging map: thread t -> (row r, 16B chunk c); SWZ'd LDS dest
  const int r0 = t >> 3,        c0 = t & 7;
  const int r1 = 32 + (t >> 3), c1 = t & 7;
  const int kof0 = r0 * 64 + ((c0 ^ SWZ8(r0)) * 8);
  const int kof1 = r1 * 64 + ((c1 ^ SWZ8(r1)) * 8);
  const unsigned short* gK0 = Kb + r0 * 64 + c0 * 8;
  const unsigned short* gK1 = Kb + r1 * 64 + c1 * 8;
  const unsigned short* gV0 = Vb + (size_t)r0 * 2048 + c0 * 8;
  const unsigned short* gV1 = Vb + (size_t)r1 * 2048 + c1 * 8;

  uint4 pk0 = *reinterpret_cast<const uint4*>(gK0);
  uint4 pk1 = *reinterpret_cast<const uint4*>(gK1);
  uint4 pv0 = *reinterpret_cast<const uint4*>(gV0);
  uint4 pv1 = *reinterpret_cast<const uint4*>(gV1);

  float l_run = 0.f;
  f32x16 o40 = {}, o41 = {};
  const int row_lo = q5, row_hi = 32 + q5;            // A-frag rows (keys / d)
  const int swz_lo = SWZ8(row_lo), swz_hi = SWZ8(row_hi);

  for (int kt = 0; kt < 32; ++kt){
    const int cur = kt & 1;
    *reinterpret_cast<uint4*>(&Ks[cur][kof0]) = pk0;
    *reinterpret_cast<uint4*>(&Ks[cur][kof1]) = pk1;
    *reinterpret_cast<uint4*>(&Vs[cur][kof0]) = pv0;
    *reinterpret_cast<uint4*>(&Vs[cur][kof1]) = pv1;
    __syncthreads();
    if (kt < 31){
      pk0 = *reinterpret_cast<const uint4*>(gK0 + (kt + 1) * 4096);
      pk1 = *reinterpret_cast<const uint4*>(gK1 + (kt + 1) * 4096);
      pv0 = *reinterpret_cast<const uint4*>(gV0 + (kt + 1) * 64);
      pv1 = *reinterpret_cast<const uint4*>(gV1 + (kt + 1) * 64);
    }

    // QK^T: S^T = K . Q^T, two 32-key blocks, 4 k-steps of 16
    f32x16 sc0 = {}, sc1 = {};
    #pragma unroll
    for (int ks = 0; ks < 4; ks++){
      const int ch = ks * 2 + hi;
      bf16x8 k0f = *reinterpret_cast<const bf16x8*>(&Ks[cur][row_lo * 64 + ((ch ^ swz_lo) * 8)]);
      bf16x8 k1f = *reinterpret_cast<const bf16x8*>(&Ks[cur][row_hi * 64 + ((ch ^ swz_hi) * 8)]);
      bf16x8 qk = (ks == 0) ? qf0 : (ks == 1) ? qf1 : (ks == 2) ? qf2 : qf3;
      sc0 = __builtin_amdgcn_mfma_f32_32x32x16_bf16(k0f, qk, sc0, 0, 0, 0);
      sc1 = __builtin_amdgcn_mfma_f32_32x32x16_bf16(k1f, qk, sc1, 0, 0, 0);
    }

    // softmax: P = exp2(s) -> packed bf16 words entirely in registers
    float psum = 0.f;
    unsigned cw0[8], cw1[8];     // sc0 / sc1 words: [a0,b0,c0,d0, a1,b1,c1,d1]
    #pragma unroll
    for (int g = 0; g < 4; g++){
      float p0 = fast_exp2(sc0[4*g+0]);
      float p1 = fast_exp2(sc0[4*g+1]);
      float p2 = fast_exp2(sc0[4*g+2]);
      float p3 = fast_exp2(sc0[4*g+3]);
      psum += (p0 + p1) + (p2 + p3);
      asm("v_cvt_pk_bf16_f32 %0, %1, %2" : "=v"(cw0[2*g])   : "v"(p0), "v"(p1));
      asm("v_cvt_pk_bf16_f32 %0, %1, %2" : "=v"(cw0[2*g+1]) : "v"(p2), "v"(p3));
    }
    #pragma unroll
    for (int g = 0; g < 4; g++){
      float p0 = fast_exp2(sc1[4*g+0]);
      float p1 = fast_exp2(sc1[4*g+1]);
      float p2 = fast_exp2(sc1[4*g+2]);
      float p3 = fast_exp2(sc1[4*g+3]);
      psum += (p0 + p1) + (p2 + p3);
      asm("v_cvt_pk_bf16_f32 %0, %1, %2" : "=v"(cw1[2*g])   : "v"(p0), "v"(p1));
      asm("v_cvt_pk_bf16_f32 %0, %1, %2" : "=v"(cw1[2*g+1]) : "v"(p2), "v"(p3));
    }
    psum += __shfl_xor(psum, 32);   // complement keys live in lane l^32 (same q)
    l_run += psum;

    // build the 4 PV B-frags via permlane32_swap (2 swaps per frag)
    // swap(a, c): ret[0] = {a_lo | c_lo} = word0, ret[1] = {a_hi | c_hi} = word2
    bf16x8 pb[4];
    #pragma unroll
    for (int ks = 0; ks < 4; ks++){
      const unsigned* cw = (ks < 2) ? cw0 : cw1;
      const int base = (ks & 1) * 4;
      const unsigned a = cw[base + 0], b2 = cw[base + 1];
      const unsigned c = cw[base + 2], d = cw[base + 3];
      u32v2 s1 = __builtin_amdgcn_permlane32_swap(a, c, false, false);   // {word0, word2}
      u32v2 s2 = __builtin_amdgcn_permlane32_swap(b2, d, false, false);  // {word1, word3}
      U8 pu;
      pu.u[0] = s1[0]; pu.u[1] = s2[0]; pu.u[2] = s1[1]; pu.u[3] = s2[1];
      pb[ks] = pu.b;
    }

    // PV: O^T = V^T . P^T
    #pragma unroll
    for (int ks = 0; ks < 4; ks++){
      const int ch = ks * 2 + hi;
      bf16x8 v0f = *reinterpret_cast<const bf16x8*>(&Vs[cur][row_lo * 64 + ((ch ^ swz_lo) * 8)]);
      bf16x8 v1f = *reinterpret_cast<const bf16x8*>(&Vs[cur][row_hi * 64 + ((ch ^ swz_hi) * 8)]);
      o40 = __builtin_amdgcn_mfma_f32_32x32x16_bf16(v0f, pb[ks], o40, 0, 0, 0);
      o41 = __builtin_amdgcn_mfma_f32_32x32x16_bf16(v1f, pb[ks], o41, 0, 0, 0);
    }
  }

  // epilogue: normalize (denominator lane-local), restage via Ks-region scratch
  // (barrier first: other waves may still read Ks/Vs), then 16B stores.
  __syncthreads();
  uint2* Eq = reinterpret_cast<uint2*>(&Ks[0][0]) + w * 512;   // 4 KB per wave
  const float rinv = 1.f / l_run;
  const int swzp = SWZ8(q5);
  #pragma unroll
  for (int g = 0; g < 4; g++){
    float a0 = o40[4*g+0] * rinv, a1 = o40[4*g+1] * rinv;
    float a2 = o40[4*g+2] * rinv, a3 = o40[4*g+3] * rinv;
    unsigned w0, w1;
    asm("v_cvt_pk_bf16_f32 %0, %1, %2" : "=v"(w0) : "v"(a0), "v"(a1));
    asm("v_cvt_pk_bf16_f32 %0, %1, %2" : "=v"(w1) : "v"(a2), "v"(a3));
    uint2 pkv; pkv.x = w0; pkv.y = w1;
    Eq[q5 * 16 + ((g ^ swzp) * 2) + hi] = pkv;
  }
  #pragma unroll
  for (int g = 0; g < 4; g++){
    float a0 = o41[4*g+0] * rinv, a1 = o41[4*g+1] * rinv;
    float a2 = o41[4*g+2] * rinv, a3 = o41[4*g+3] * rinv;
    unsigned w0, w1;
    asm("v_cvt_pk_bf16_f32 %0, %1, %2" : "=v"(w0) : "v"(a0), "v"(a1));
    asm("v_cvt_pk_bf16_f32 %0, %1, %2" : "=v"(w1) : "v"(a2), "v"(a3));
    uint2 pkv; pkv.x = w0; pkv.y = w1;
    Eq[q5 * 16 + (((4 + g) ^ swzp) * 2) + hi] = pkv;
  }
  const int qr = l >> 1;             // 0..31: O row within wave tile
  const int cbase = (l & 1) * 4;     // chunks 0..3 / 4..7
  const int swzq = SWZ8(qr);
  const int b = bh >> 4, h = bh & 15;
  unsigned short* Ob = O + ((size_t)b * 2048 + q0 + qr) * 1024 + h * 64;
  #pragma unroll
  for (int cc = 0; cc < 4; ++cc){
    const int c = cbase + cc;
    const int base = qr * 16 + ((c ^ swzq) * 2);
    uint2 lo = Eq[base];
    uint2 hi2 = Eq[base + 1];
    uint4 xv; xv.x = lo.x; xv.y = lo.y; xv.z = hi2.x; xv.w = hi2.y;
    *reinterpret_cast<uint4*>(Ob + c * 8) = xv;
  }
}

extern "C" void kernel_launch(void* const* d_in, const int* in_sizes, int n_in,
                              void* d_out, int out_size, void* d_ws, size_t ws_size,
                              hipStream_t stream){
  const float* query = (const float*)d_in[0];
  const float* Wqkv  = (const float*)d_in[1];
  const float* bqkv  = (const float*)d_in[2];
  const float* Wout  = (const float*)d_in[3];
  const float* bout  = (const float*)d_in[4];
  float* out = (float*)d_out;

  unsigned short* ws    = (unsigned short*)d_ws;
  unsigned short* xbf   = ws;                      // 4096x1024 (query bf16; dead after gemm<0> -> attn out)
  unsigned short* wqkvT = xbf   + 4194304;         // 3072x1024
  unsigned short* woutT = wqkvT + 3145728;         // 1024x1024
  unsigned short* qbf   = woutT + 1048576;         // [32][2048][64]
  unsigned short* kbf   = qbf   + 4194304;         // [32][2048][64]
  unsigned short* vtbf  = kbf   + 4194304;         // [32][64][2048]
  unsigned short* abf   = xbf;                     // attn out aliases dead xbf

  prep<<<3072, 256, 0, stream>>>(query, Wqkv, Wout, xbf, wqkvT, woutT);
  gemm_bt<0><<<dim3(24, 32), 256, 0, stream>>>(xbf, wqkvT, bqkv, qbf, kbf, vtbf, nullptr);
  attn_fwd<<<dim3(16, 32), 256, 0, stream>>>(qbf, kbf, vtbf, abf);
  gemm_bt<1><<<dim3(16, 32), 256, 0, stream>>>(abf, woutT, bout, nullptr, nullptr, nullptr, out);
}